// Round 12
// baseline (296.132 us; speedup 1.0000x reference)
//
#include <hip/hip_runtime.h>

#define KCLS 19
#define CCH 64
#define HW (512*512)
#define NPIX (4*HW)

// K1 geometry: lane = channel
#define NWAVE 4
#define WPX 256                 // pixels per wave
#define BPX (NWAVE * WPX)       // 1024 pixels per block
#define NBLK (NPIX / BPX)       // 1024 blocks
#define NBLK3 1024

// ws float offsets (stats area)
#define WS_COUNTS  0      // 19
#define WS_SUMS    32     // [k*64+c], 1216
#define WS_VARSUM  1280   // 19
#define WS_NFLOATS 2576
#define WS_FP8_BYTE_OFF 16384   // fp8 copy of pred, wave-local layout: 64 MB

typedef float f32x2 __attribute__((ext_vector_type(2)));
typedef float f32x4 __attribute__((ext_vector_type(4)));
typedef unsigned u32x4 __attribute__((ext_vector_type(4)));

__device__ __forceinline__ void ldsAdd(float* p, float v) { unsafeAtomicAdd(p, v); }

// ---------------- K0: zero stats ----------------
__global__ __launch_bounds__(256) void k0_zero(float* __restrict__ ws) {
    for (int i = threadIdx.x; i < WS_NFLOATS; i += 256) ws[i] = 0.0f;
}

// ---------------- K1: counts + sums + fp8 copy; prefetch + non-temporal stream ----------------
// block 256 (4 waves); wave handles 256 contiguous pixels; lane = channel.
// fp8 word (i,l) -> fp8buf[blk*16384 + w*4096 + i*64 + l]: lane-consecutive NT stores.
__global__ __launch_bounds__(256) void k1_sums(const float* __restrict__ pred,
                                               const int* __restrict__ tgt,
                                               float* __restrict__ ws,
                                               unsigned* __restrict__ fp8buf) {
    const int t = threadIdx.x;
    const int l = t & 63;            // lane -> channel
    const int w = t >> 6;            // wave id
    const int base_px = blockIdx.x * BPX;
    const int n = base_px / HW;
    const int hwb = base_px - n * HW;

    __shared__ unsigned labw[BPX / 4];        // 1 KB packed u8 labels
    __shared__ float bins[NWAVE][64 * 21];    // 21.5 KB
    __shared__ float cnt[16 * 21];            // 1.3 KB

    float* bw = bins[w];
    #pragma unroll
    for (int k = 0; k < 21; ++k) bw[l * 21 + k] = 0.0f;
    for (int i = t; i < 16 * 21; i += 256) cnt[i] = 0.0f;
    __syncthreads();

    // stage labels (packed u8) + count histogram via ds_add_f32 (16 replicas)
    {
        int4 L = ((const int4*)(tgt + base_px))[t];
        labw[t] = (unsigned)(L.x & 0xFF) | ((unsigned)(L.y & 0xFF) << 8) |
                  ((unsigned)(L.z & 0xFF) << 16) | ((unsigned)(L.w & 0xFF) << 24);
        float* cr = &cnt[(t & 15) * 21];
        ldsAdd(&cr[L.x & 31], 1.0f);
        ldsAdd(&cr[L.y & 31], 1.0f);
        ldsAdd(&cr[L.z & 31], 1.0f);
        ldsAdd(&cr[L.w & 31], 1.0f);
    }
    __syncthreads();

    // main loop: 16 batches of 4 f32x4-iters, next-batch register prefetch, NT loads/stores
    const f32x4* src = (const f32x4*)(pred + (size_t)(n * CCH + l) * HW + hwb + w * WPX);
    unsigned* dst8 = fp8buf + (size_t)blockIdx.x * 16384 + w * 4096;
    const unsigned* lwp = &labw[w * 64];
    float* br = &bw[l * 21];

    f32x4 v0 = __builtin_nontemporal_load(&src[0]);
    f32x4 v1 = __builtin_nontemporal_load(&src[1]);
    f32x4 v2 = __builtin_nontemporal_load(&src[2]);
    f32x4 v3 = __builtin_nontemporal_load(&src[3]);
    unsigned lw0 = lwp[0], lw1 = lwp[1], lw2 = lwp[2], lw3 = lwp[3];

    for (int ib = 0; ib < 16; ++ib) {
        f32x4 n0, n1, n2, n3;
        unsigned m0, m1, m2, m3;
        if (ib < 15) {                       // issue next-batch loads FIRST
            const int q = (ib + 1) * 4;
            n0 = __builtin_nontemporal_load(&src[q]);
            n1 = __builtin_nontemporal_load(&src[q + 1]);
            n2 = __builtin_nontemporal_load(&src[q + 2]);
            n3 = __builtin_nontemporal_load(&src[q + 3]);
            m0 = lwp[q]; m1 = lwp[q + 1]; m2 = lwp[q + 2]; m3 = lwp[q + 3];
        }
        const int qb = ib * 4;
        {
            const int b0 = lw0 & 31, b1 = (lw0 >> 8) & 31, b2 = (lw0 >> 16) & 31, b3 = (lw0 >> 24) & 31;
            br[b0] += v0[0]; br[b1] += v0[1]; br[b2] += v0[2]; br[b3] += v0[3];
            int pk = 0;
            pk = __builtin_amdgcn_cvt_pk_fp8_f32(v0[0], v0[1], pk, false);
            pk = __builtin_amdgcn_cvt_pk_fp8_f32(v0[2], v0[3], pk, true);
            __builtin_nontemporal_store((unsigned)pk, &dst8[qb * 64 + l]);
        }
        {
            const int b0 = lw1 & 31, b1 = (lw1 >> 8) & 31, b2 = (lw1 >> 16) & 31, b3 = (lw1 >> 24) & 31;
            br[b0] += v1[0]; br[b1] += v1[1]; br[b2] += v1[2]; br[b3] += v1[3];
            int pk = 0;
            pk = __builtin_amdgcn_cvt_pk_fp8_f32(v1[0], v1[1], pk, false);
            pk = __builtin_amdgcn_cvt_pk_fp8_f32(v1[2], v1[3], pk, true);
            __builtin_nontemporal_store((unsigned)pk, &dst8[(qb + 1) * 64 + l]);
        }
        {
            const int b0 = lw2 & 31, b1 = (lw2 >> 8) & 31, b2 = (lw2 >> 16) & 31, b3 = (lw2 >> 24) & 31;
            br[b0] += v2[0]; br[b1] += v2[1]; br[b2] += v2[2]; br[b3] += v2[3];
            int pk = 0;
            pk = __builtin_amdgcn_cvt_pk_fp8_f32(v2[0], v2[1], pk, false);
            pk = __builtin_amdgcn_cvt_pk_fp8_f32(v2[2], v2[3], pk, true);
            __builtin_nontemporal_store((unsigned)pk, &dst8[(qb + 2) * 64 + l]);
        }
        {
            const int b0 = lw3 & 31, b1 = (lw3 >> 8) & 31, b2 = (lw3 >> 16) & 31, b3 = (lw3 >> 24) & 31;
            br[b0] += v3[0]; br[b1] += v3[1]; br[b2] += v3[2]; br[b3] += v3[3];
            int pk = 0;
            pk = __builtin_amdgcn_cvt_pk_fp8_f32(v3[0], v3[1], pk, false);
            pk = __builtin_amdgcn_cvt_pk_fp8_f32(v3[2], v3[3], pk, true);
            __builtin_nontemporal_store((unsigned)pk, &dst8[(qb + 3) * 64 + l]);
        }
        v0 = n0; v1 = n1; v2 = n2; v3 = n3;
        lw0 = m0; lw1 = m1; lw2 = m2; lw3 = m3;
    }
    __syncthreads();

    // flush: sums (1216) and counts (19)
    for (int idx = t; idx < KCLS * CCH; idx += 256) {
        const int k = idx >> 6, c = idx & 63;
        float s = bins[0][c * 21 + k] + bins[1][c * 21 + k] +
                  bins[2][c * 21 + k] + bins[3][c * 21 + k];
        unsafeAtomicAdd(&ws[WS_SUMS + idx], s);
    }
    if (t < KCLS) {
        float s = 0.0f;
        #pragma unroll
        for (int r = 0; r < 16; ++r) s += cnt[r * 21 + t];
        unsafeAtomicAdd(&ws[WS_COUNTS + t], s);
    }
}

// ---------------- K3: pull term from fp8 copy (mirrors k1 layout, NT loads) ----------------
__global__ __launch_bounds__(256) void k3_var(const unsigned* __restrict__ fp8buf,
                                              const int* __restrict__ tgt,
                                              float* __restrict__ ws) {
    const int t = threadIdx.x;
    const int l = t & 63;
    const int w = t >> 6;
    const int cid = (NBLK3 - 1) - blockIdx.x;
    const int base_px = cid * BPX;

    __shared__ float ct[KCLS * CCH];     // [k][c] -> float4 reads at (lab*64 + 4*(l&15))
    __shared__ float cntS[KCLS];
    __shared__ unsigned labw[256];
    __shared__ float varh[64 * 21];      // 64 unique replicas (w,cohort,q) -> plain RMW

    if (t < KCLS) cntS[t] = ws[WS_COUNTS + t];
    for (int i = t; i < 64 * 21; i += 256) varh[i] = 0.0f;
    __syncthreads();
    for (int i = t; i < KCLS * CCH; i += 256)
        ct[i] = ws[WS_SUMS + i] / fmaxf(cntS[i >> 6], 1.0f);
    {
        int4 L = ((const int4*)(tgt + base_px))[t];
        labw[t] = (unsigned)(L.x & 0xFF) | ((unsigned)(L.y & 0xFF) << 8) |
                  ((unsigned)(L.z & 0xFF) << 16) | ((unsigned)(L.w & 0xFF) << 24);
    }
    __syncthreads();

    const u32x4* src = (const u32x4*)(fp8buf + (size_t)cid * 16384 + w * 4096);
    const int coh = l >> 4;              // cohort 0..3
    const int q16 = l & 15;
    const int ch0 = q16 * 4;             // this lane's 4 channels
    float* myrep = &varh[(w * 16 + coh * 4) * 21];

    for (int j = 0; j < 16; ++j) {
        const u32x4 W = __builtin_nontemporal_load(&src[j * 64 + l]);
        const unsigned lw = labw[w * 64 + j * 4 + coh];
        const int lab0 = lw & 31, lab1 = (lw >> 8) & 31, lab2 = (lw >> 16) & 31, lab3 = (lw >> 24) & 31;
        const float4 m0 = *(const float4*)&ct[lab0 * CCH + ch0];
        const float4 m1 = *(const float4*)&ct[lab1 * CCH + ch0];
        const float4 m2 = *(const float4*)&ct[lab2 * CCH + ch0];
        const float4 m3 = *(const float4*)&ct[lab3 * CCH + ch0];
        f32x2 x0lo = __builtin_amdgcn_cvt_pk_f32_fp8(W[0], false), x0hi = __builtin_amdgcn_cvt_pk_f32_fp8(W[0], true);
        f32x2 x1lo = __builtin_amdgcn_cvt_pk_f32_fp8(W[1], false), x1hi = __builtin_amdgcn_cvt_pk_f32_fp8(W[1], true);
        f32x2 x2lo = __builtin_amdgcn_cvt_pk_f32_fp8(W[2], false), x2hi = __builtin_amdgcn_cvt_pk_f32_fp8(W[2], true);
        f32x2 x3lo = __builtin_amdgcn_cvt_pk_f32_fp8(W[3], false), x3hi = __builtin_amdgcn_cvt_pk_f32_fp8(W[3], true);
        float a0, a1, a2, a3, d;
        d = x0lo.x - m0.x; a0 = d * d;
        d = x1lo.x - m0.y; a0 = fmaf(d, d, a0);
        d = x2lo.x - m0.z; a0 = fmaf(d, d, a0);
        d = x3lo.x - m0.w; a0 = fmaf(d, d, a0);
        d = x0lo.y - m1.x; a1 = d * d;
        d = x1lo.y - m1.y; a1 = fmaf(d, d, a1);
        d = x2lo.y - m1.z; a1 = fmaf(d, d, a1);
        d = x3lo.y - m1.w; a1 = fmaf(d, d, a1);
        d = x0hi.x - m2.x; a2 = d * d;
        d = x1hi.x - m2.y; a2 = fmaf(d, d, a2);
        d = x2hi.x - m2.z; a2 = fmaf(d, d, a2);
        d = x3hi.x - m2.w; a2 = fmaf(d, d, a2);
        d = x0hi.y - m3.x; a3 = d * d;
        d = x1hi.y - m3.y; a3 = fmaf(d, d, a3);
        d = x2hi.y - m3.z; a3 = fmaf(d, d, a3);
        d = x3hi.y - m3.w; a3 = fmaf(d, d, a3);
        #pragma unroll
        for (int m = 1; m < 16; m <<= 1) {
            a0 += __shfl_xor(a0, m, 16);
            a1 += __shfl_xor(a1, m, 16);
            a2 += __shfl_xor(a2, m, 16);
            a3 += __shfl_xor(a3, m, 16);
        }
        if (q16 < 4) {
            float a = (q16 == 0) ? a0 : (q16 == 1) ? a1 : (q16 == 2) ? a2 : a3;
            int lab = (q16 == 0) ? lab0 : (q16 == 1) ? lab1 : (q16 == 2) ? lab2 : lab3;
            float dd = sqrtf(fmaxf(a, 1e-12f));
            float r = dd - 0.5f;
            if (r > 0.0f) myrep[q16 * 21 + lab] += r * r;
        }
    }
    __syncthreads();
    if (t < KCLS) {
        float s = 0.0f;
        for (int r = 0; r < 64; ++r) s += varh[r * 21 + t];
        unsafeAtomicAdd(&ws[WS_VARSUM + t], s);
    }
}

// ---------------- K4: centers + push + reg + final combine (1 block) ----------------
__global__ __launch_bounds__(256) void k4_final(const float* __restrict__ ws,
                                                float* __restrict__ out) {
    __shared__ float ct[CCH * 20];
    __shared__ float cntS[KCLS];
    __shared__ float acc[2];
    const int t = threadIdx.x;
    if (t < KCLS) cntS[t] = ws[WS_COUNTS + t];
    if (t < 2) acc[t] = 0.0f;
    __syncthreads();
    for (int i = t; i < CCH * 20; i += 256) {
        int c = i / 20, k = i % 20;
        ct[i] = (k < KCLS) ? ws[WS_SUMS + k * CCH + c] / fmaxf(cntS[k], 1.0f) : 0.0f;
    }
    __syncthreads();

    for (int p = t; p < KCLS * KCLS; p += 256) {
        int i = p / KCLS, j = p % KCLS;
        if (i != j && cntS[i] > 20.0f && cntS[j] > 20.0f) {
            float sq = 0.0f;
            #pragma unroll 8
            for (int c = 0; c < CCH; ++c) {
                float d = ct[c * 20 + i] - ct[c * 20 + j];
                sq = fmaf(d, d, sq);
            }
            float pd = sqrtf(sq);
            float r = 3.0f - pd;        // 2*DELTA - pd
            if (r > 0.0f) atomicAdd(&acc[0], r * r);
        }
    }
    if (t < KCLS && cntS[t] > 20.0f) {
        float sq = 0.0f;
        #pragma unroll 8
        for (int c = 0; c < CCH; ++c) { float v = ct[c * 20 + t]; sq = fmaf(v, v, sq); }
        atomicAdd(&acc[1], sqrtf(sq));
    }
    __syncthreads();

    if (t < 64) {
        float v = 0.0f;
        if (t < KCLS) {
            float c = cntS[t];
            if (c > 20.0f) v = ws[WS_VARSUM + t] / fmaxf(c, 1.0f);
        }
        #pragma unroll
        for (int s = 32; s > 0; s >>= 1) v += __shfl_down(v, s);
        if (t == 0) {
            float nv = 0.0f;
            for (int k = 0; k < KCLS; ++k) nv += (cntS[k] > 20.0f) ? 1.0f : 0.0f;
            float loss_dis = acc[0] / fmaxf(nv * (nv - 1.0f), 1.0f);
            float loss_reg = acc[1] / fmaxf(nv, 1.0f);
            out[0] = v / fmaxf(nv, 1.0f) + loss_dis + 0.001f * loss_reg;
        }
    }
}

extern "C" void kernel_launch(void* const* d_in, const int* in_sizes, int n_in,
                              void* d_out, int out_size, void* d_ws, size_t ws_size,
                              hipStream_t stream) {
    const float* pred = (const float*)d_in[0];
    const int* tgt = (const int*)d_in[1];
    float* ws = (float*)d_ws;
    unsigned* fp8buf = (unsigned*)((char*)d_ws + WS_FP8_BYTE_OFF);
    float* out = (float*)d_out;

    hipLaunchKernelGGL(k0_zero, dim3(1), dim3(256), 0, stream, ws);
    hipLaunchKernelGGL(k1_sums, dim3(NBLK), dim3(256), 0, stream, pred, tgt, ws, fp8buf);
    hipLaunchKernelGGL(k3_var, dim3(NBLK3), dim3(256), 0, stream, fp8buf, tgt, ws);
    hipLaunchKernelGGL(k4_final, dim3(1), dim3(256), 0, stream, ws, out);
}

// Round 13
// 148.303 us; speedup vs baseline: 1.9968x; 1.9968x over previous
//
#include <hip/hip_runtime.h>

#define KCLS 19
#define CCH 64
#define HW (512*512)
#define NPIX (4*HW)

// K1 geometry: lane = channel
#define NWAVE 4
#define WPX 256                 // pixels per wave
#define BPX (NWAVE * WPX)       // 1024 pixels per block
#define NBLK (NPIX / BPX)       // 1024 blocks
#define NBLK3 1024

// ws float offsets (stats area)
#define WS_COUNTS  0      // 19
#define WS_SUMS    32     // [k*64+c], 1216
#define WS_VARSUM  1280   // 19
#define WS_NFLOATS 2576
#define WS_FP8_BYTE_OFF 16384   // fp8 copy of pred, wave-local layout: 64 MB

typedef float f32x2 __attribute__((ext_vector_type(2)));

__device__ __forceinline__ void ldsAdd(float* p, float v) { unsafeAtomicAdd(p, v); }

// ---------------- K0: zero stats ----------------
__global__ __launch_bounds__(256) void k0_zero(float* __restrict__ ws) {
    for (int i = threadIdx.x; i < WS_NFLOATS; i += 256) ws[i] = 0.0f;
}

// ---------------- K1: counts + sums + fp8 copy; prefetch; NT on STORES only ----------------
// block 256 (4 waves); wave handles 256 contiguous pixels; lane = channel.
// fp8 word (i,l) -> fp8buf[blk*16384 + w*4096 + i*64 + l]: lane-consecutive NT stores.
__global__ __launch_bounds__(256) void k1_sums(const float* __restrict__ pred,
                                               const int* __restrict__ tgt,
                                               float* __restrict__ ws,
                                               unsigned* __restrict__ fp8buf) {
    const int t = threadIdx.x;
    const int l = t & 63;            // lane -> channel
    const int w = t >> 6;            // wave id
    const int base_px = blockIdx.x * BPX;
    const int n = base_px / HW;
    const int hwb = base_px - n * HW;

    __shared__ unsigned labw[BPX / 4];        // 1 KB packed u8 labels
    __shared__ float bins[NWAVE][64 * 21];    // 21.5 KB
    __shared__ float cnt[16 * 21];            // 1.3 KB

    float* bw = bins[w];
    #pragma unroll
    for (int k = 0; k < 21; ++k) bw[l * 21 + k] = 0.0f;
    for (int i = t; i < 16 * 21; i += 256) cnt[i] = 0.0f;
    __syncthreads();

    // stage labels (packed u8) + count histogram via ds_add_f32 (16 replicas)
    {
        int4 L = ((const int4*)(tgt + base_px))[t];
        labw[t] = (unsigned)(L.x & 0xFF) | ((unsigned)(L.y & 0xFF) << 8) |
                  ((unsigned)(L.z & 0xFF) << 16) | ((unsigned)(L.w & 0xFF) << 24);
        float* cr = &cnt[(t & 15) * 21];
        ldsAdd(&cr[L.x & 31], 1.0f);
        ldsAdd(&cr[L.y & 31], 1.0f);
        ldsAdd(&cr[L.z & 31], 1.0f);
        ldsAdd(&cr[L.w & 31], 1.0f);
    }
    __syncthreads();

    // main loop: 16 batches of 4 float4-iters, next-batch register prefetch
    const float4* src = (const float4*)(pred + (size_t)(n * CCH + l) * HW + hwb + w * WPX);
    unsigned* dst8 = fp8buf + (size_t)blockIdx.x * 16384 + w * 4096;
    const unsigned* lwp = &labw[w * 64];
    float* br = &bw[l * 21];

    float4 v0 = src[0], v1 = src[1], v2 = src[2], v3 = src[3];
    unsigned lw0 = lwp[0], lw1 = lwp[1], lw2 = lwp[2], lw3 = lwp[3];

    for (int ib = 0; ib < 16; ++ib) {
        float4 n0, n1, n2, n3;
        unsigned m0, m1, m2, m3;
        if (ib < 15) {                       // issue next-batch loads FIRST
            const int q = (ib + 1) * 4;
            n0 = src[q]; n1 = src[q + 1]; n2 = src[q + 2]; n3 = src[q + 3];
            m0 = lwp[q]; m1 = lwp[q + 1]; m2 = lwp[q + 2]; m3 = lwp[q + 3];
        }
        const int qb = ib * 4;
        {
            const int b0 = lw0 & 31, b1 = (lw0 >> 8) & 31, b2 = (lw0 >> 16) & 31, b3 = (lw0 >> 24) & 31;
            br[b0] += v0.x; br[b1] += v0.y; br[b2] += v0.z; br[b3] += v0.w;
            int pk = 0;
            pk = __builtin_amdgcn_cvt_pk_fp8_f32(v0.x, v0.y, pk, false);
            pk = __builtin_amdgcn_cvt_pk_fp8_f32(v0.z, v0.w, pk, true);
            __builtin_nontemporal_store((unsigned)pk, &dst8[qb * 64 + l]);
        }
        {
            const int b0 = lw1 & 31, b1 = (lw1 >> 8) & 31, b2 = (lw1 >> 16) & 31, b3 = (lw1 >> 24) & 31;
            br[b0] += v1.x; br[b1] += v1.y; br[b2] += v1.z; br[b3] += v1.w;
            int pk = 0;
            pk = __builtin_amdgcn_cvt_pk_fp8_f32(v1.x, v1.y, pk, false);
            pk = __builtin_amdgcn_cvt_pk_fp8_f32(v1.z, v1.w, pk, true);
            __builtin_nontemporal_store((unsigned)pk, &dst8[(qb + 1) * 64 + l]);
        }
        {
            const int b0 = lw2 & 31, b1 = (lw2 >> 8) & 31, b2 = (lw2 >> 16) & 31, b3 = (lw2 >> 24) & 31;
            br[b0] += v2.x; br[b1] += v2.y; br[b2] += v2.z; br[b3] += v2.w;
            int pk = 0;
            pk = __builtin_amdgcn_cvt_pk_fp8_f32(v2.x, v2.y, pk, false);
            pk = __builtin_amdgcn_cvt_pk_fp8_f32(v2.z, v2.w, pk, true);
            __builtin_nontemporal_store((unsigned)pk, &dst8[(qb + 2) * 64 + l]);
        }
        {
            const int b0 = lw3 & 31, b1 = (lw3 >> 8) & 31, b2 = (lw3 >> 16) & 31, b3 = (lw3 >> 24) & 31;
            br[b0] += v3.x; br[b1] += v3.y; br[b2] += v3.z; br[b3] += v3.w;
            int pk = 0;
            pk = __builtin_amdgcn_cvt_pk_fp8_f32(v3.x, v3.y, pk, false);
            pk = __builtin_amdgcn_cvt_pk_fp8_f32(v3.z, v3.w, pk, true);
            __builtin_nontemporal_store((unsigned)pk, &dst8[(qb + 3) * 64 + l]);
        }
        v0 = n0; v1 = n1; v2 = n2; v3 = n3;
        lw0 = m0; lw1 = m1; lw2 = m2; lw3 = m3;
    }
    __syncthreads();

    // flush: sums (1216) and counts (19)
    for (int idx = t; idx < KCLS * CCH; idx += 256) {
        const int k = idx >> 6, c = idx & 63;
        float s = bins[0][c * 21 + k] + bins[1][c * 21 + k] +
                  bins[2][c * 21 + k] + bins[3][c * 21 + k];
        unsafeAtomicAdd(&ws[WS_SUMS + idx], s);
    }
    if (t < KCLS) {
        float s = 0.0f;
        #pragma unroll
        for (int r = 0; r < 16; ++r) s += cnt[r * 21 + t];
        unsafeAtomicAdd(&ws[WS_COUNTS + t], s);
    }
}

// ---------------- K3: pull term from fp8 copy (mirrors k1 layout, plain loads) ----------------
__global__ __launch_bounds__(256) void k3_var(const unsigned* __restrict__ fp8buf,
                                              const int* __restrict__ tgt,
                                              float* __restrict__ ws) {
    const int t = threadIdx.x;
    const int l = t & 63;
    const int w = t >> 6;
    const int cid = (NBLK3 - 1) - blockIdx.x;
    const int base_px = cid * BPX;

    __shared__ float ct[KCLS * CCH];     // [k][c] -> float4 reads at (lab*64 + 4*(l&15))
    __shared__ float cntS[KCLS];
    __shared__ unsigned labw[256];
    __shared__ float varh[64 * 21];      // 64 unique replicas (w,cohort,q) -> plain RMW

    if (t < KCLS) cntS[t] = ws[WS_COUNTS + t];
    for (int i = t; i < 64 * 21; i += 256) varh[i] = 0.0f;
    __syncthreads();
    for (int i = t; i < KCLS * CCH; i += 256)
        ct[i] = ws[WS_SUMS + i] / fmaxf(cntS[i >> 6], 1.0f);
    {
        int4 L = ((const int4*)(tgt + base_px))[t];
        labw[t] = (unsigned)(L.x & 0xFF) | ((unsigned)(L.y & 0xFF) << 8) |
                  ((unsigned)(L.z & 0xFF) << 16) | ((unsigned)(L.w & 0xFF) << 24);
    }
    __syncthreads();

    const uint4* src = (const uint4*)(fp8buf + (size_t)cid * 16384 + w * 4096);
    const int coh = l >> 4;              // cohort 0..3
    const int q16 = l & 15;
    const int ch0 = q16 * 4;             // this lane's 4 channels
    float* myrep = &varh[(w * 16 + coh * 4) * 21];

    for (int j = 0; j < 16; ++j) {
        const uint4 W = src[j * 64 + l];
        const unsigned lw = labw[w * 64 + j * 4 + coh];
        const int lab0 = lw & 31, lab1 = (lw >> 8) & 31, lab2 = (lw >> 16) & 31, lab3 = (lw >> 24) & 31;
        const float4 m0 = *(const float4*)&ct[lab0 * CCH + ch0];
        const float4 m1 = *(const float4*)&ct[lab1 * CCH + ch0];
        const float4 m2 = *(const float4*)&ct[lab2 * CCH + ch0];
        const float4 m3 = *(const float4*)&ct[lab3 * CCH + ch0];
        f32x2 x0lo = __builtin_amdgcn_cvt_pk_f32_fp8(W.x, false), x0hi = __builtin_amdgcn_cvt_pk_f32_fp8(W.x, true);
        f32x2 x1lo = __builtin_amdgcn_cvt_pk_f32_fp8(W.y, false), x1hi = __builtin_amdgcn_cvt_pk_f32_fp8(W.y, true);
        f32x2 x2lo = __builtin_amdgcn_cvt_pk_f32_fp8(W.z, false), x2hi = __builtin_amdgcn_cvt_pk_f32_fp8(W.z, true);
        f32x2 x3lo = __builtin_amdgcn_cvt_pk_f32_fp8(W.w, false), x3hi = __builtin_amdgcn_cvt_pk_f32_fp8(W.w, true);
        float a0, a1, a2, a3, d;
        d = x0lo.x - m0.x; a0 = d * d;
        d = x1lo.x - m0.y; a0 = fmaf(d, d, a0);
        d = x2lo.x - m0.z; a0 = fmaf(d, d, a0);
        d = x3lo.x - m0.w; a0 = fmaf(d, d, a0);
        d = x0lo.y - m1.x; a1 = d * d;
        d = x1lo.y - m1.y; a1 = fmaf(d, d, a1);
        d = x2lo.y - m1.z; a1 = fmaf(d, d, a1);
        d = x3lo.y - m1.w; a1 = fmaf(d, d, a1);
        d = x0hi.x - m2.x; a2 = d * d;
        d = x1hi.x - m2.y; a2 = fmaf(d, d, a2);
        d = x2hi.x - m2.z; a2 = fmaf(d, d, a2);
        d = x3hi.x - m2.w; a2 = fmaf(d, d, a2);
        d = x0hi.y - m3.x; a3 = d * d;
        d = x1hi.y - m3.y; a3 = fmaf(d, d, a3);
        d = x2hi.y - m3.z; a3 = fmaf(d, d, a3);
        d = x3hi.y - m3.w; a3 = fmaf(d, d, a3);
        #pragma unroll
        for (int m = 1; m < 16; m <<= 1) {
            a0 += __shfl_xor(a0, m, 16);
            a1 += __shfl_xor(a1, m, 16);
            a2 += __shfl_xor(a2, m, 16);
            a3 += __shfl_xor(a3, m, 16);
        }
        if (q16 < 4) {
            float a = (q16 == 0) ? a0 : (q16 == 1) ? a1 : (q16 == 2) ? a2 : a3;
            int lab = (q16 == 0) ? lab0 : (q16 == 1) ? lab1 : (q16 == 2) ? lab2 : lab3;
            float dd = sqrtf(fmaxf(a, 1e-12f));
            float r = dd - 0.5f;
            if (r > 0.0f) myrep[q16 * 21 + lab] += r * r;
        }
    }
    __syncthreads();
    if (t < KCLS) {
        float s = 0.0f;
        for (int r = 0; r < 64; ++r) s += varh[r * 21 + t];
        unsafeAtomicAdd(&ws[WS_VARSUM + t], s);
    }
}

// ---------------- K4: centers + push + reg + final combine (1 block) ----------------
__global__ __launch_bounds__(256) void k4_final(const float* __restrict__ ws,
                                                float* __restrict__ out) {
    __shared__ float ct[CCH * 20];
    __shared__ float cntS[KCLS];
    __shared__ float acc[2];
    const int t = threadIdx.x;
    if (t < KCLS) cntS[t] = ws[WS_COUNTS + t];
    if (t < 2) acc[t] = 0.0f;
    __syncthreads();
    for (int i = t; i < CCH * 20; i += 256) {
        int c = i / 20, k = i % 20;
        ct[i] = (k < KCLS) ? ws[WS_SUMS + k * CCH + c] / fmaxf(cntS[k], 1.0f) : 0.0f;
    }
    __syncthreads();

    for (int p = t; p < KCLS * KCLS; p += 256) {
        int i = p / KCLS, j = p % KCLS;
        if (i != j && cntS[i] > 20.0f && cntS[j] > 20.0f) {
            float sq = 0.0f;
            #pragma unroll 8
            for (int c = 0; c < CCH; ++c) {
                float d = ct[c * 20 + i] - ct[c * 20 + j];
                sq = fmaf(d, d, sq);
            }
            float pd = sqrtf(sq);
            float r = 3.0f - pd;        // 2*DELTA - pd
            if (r > 0.0f) atomicAdd(&acc[0], r * r);
        }
    }
    if (t < KCLS && cntS[t] > 20.0f) {
        float sq = 0.0f;
        #pragma unroll 8
        for (int c = 0; c < CCH; ++c) { float v = ct[c * 20 + t]; sq = fmaf(v, v, sq); }
        atomicAdd(&acc[1], sqrtf(sq));
    }
    __syncthreads();

    if (t < 64) {
        float v = 0.0f;
        if (t < KCLS) {
            float c = cntS[t];
            if (c > 20.0f) v = ws[WS_VARSUM + t] / fmaxf(c, 1.0f);
        }
        #pragma unroll
        for (int s = 32; s > 0; s >>= 1) v += __shfl_down(v, s);
        if (t == 0) {
            float nv = 0.0f;
            for (int k = 0; k < KCLS; ++k) nv += (cntS[k] > 20.0f) ? 1.0f : 0.0f;
            float loss_dis = acc[0] / fmaxf(nv * (nv - 1.0f), 1.0f);
            float loss_reg = acc[1] / fmaxf(nv, 1.0f);
            out[0] = v / fmaxf(nv, 1.0f) + loss_dis + 0.001f * loss_reg;
        }
    }
}

extern "C" void kernel_launch(void* const* d_in, const int* in_sizes, int n_in,
                              void* d_out, int out_size, void* d_ws, size_t ws_size,
                              hipStream_t stream) {
    const float* pred = (const float*)d_in[0];
    const int* tgt = (const int*)d_in[1];
    float* ws = (float*)d_ws;
    unsigned* fp8buf = (unsigned*)((char*)d_ws + WS_FP8_BYTE_OFF);
    float* out = (float*)d_out;

    hipLaunchKernelGGL(k0_zero, dim3(1), dim3(256), 0, stream, ws);
    hipLaunchKernelGGL(k1_sums, dim3(NBLK), dim3(256), 0, stream, pred, tgt, ws, fp8buf);
    hipLaunchKernelGGL(k3_var, dim3(NBLK3), dim3(256), 0, stream, fp8buf, tgt, ws);
    hipLaunchKernelGGL(k4_final, dim3(1), dim3(256), 0, stream, ws, out);
}

// Round 14
// 130.399 us; speedup vs baseline: 2.2710x; 1.1373x over previous
//
#include <hip/hip_runtime.h>

#define KCLS 19
#define CCH 64
#define HW (512*512)
#define NPIX (4*HW)          // 1,048,576 pixels

// K1 geometry: channel-major contiguous
#define CHUNK 16384          // pixels per chunk (16 chunks per image)
#define NCHUNK (NPIX/CHUNK)  // 64
#define NCGRP 16             // channel groups of 4
#define CPG 4

// ws float offsets (stats area)
#define WS_COUNTS  0      // 19
#define WS_SUMS    32     // [k*64+c], 1216
#define WS_VARSUM  1280   // 19
#define WS_NFLOATS 2576
#define WS_U8_BYTE_OFF 16384   // packed u8 labels, 1 MB

__device__ __forceinline__ void ldsAdd(float* p, float v) { unsafeAtomicAdd(p, v); }

// ---------------- K0: zero stats + pack labels to u8 ----------------
// grid 256 x 256 thr; thread j packs 4 u32 words (16 labels) -> uint4 store
__global__ __launch_bounds__(256) void k0_prep(const int* __restrict__ tgt,
                                               float* __restrict__ ws,
                                               unsigned* __restrict__ u8buf) {
    const int j = blockIdx.x * 256 + threadIdx.x;
    if (blockIdx.x == 0) {
        for (int i = threadIdx.x; i < WS_NFLOATS; i += 256) ws[i] = 0.0f;
    }
    const int4* tg4 = (const int4*)tgt;
    unsigned pk[4];
    #pragma unroll
    for (int q = 0; q < 4; ++q) {
        int4 L = tg4[j * 4 + q];
        pk[q] = (unsigned)(L.x & 0xFF) | ((unsigned)(L.y & 0xFF) << 8) |
                ((unsigned)(L.z & 0xFF) << 16) | ((unsigned)(L.w & 0xFF) << 24);
    }
    uint4 o; o.x = pk[0]; o.y = pk[1]; o.z = pk[2]; o.w = pk[3];
    ((uint4*)u8buf)[j] = o;
}

// ---------------- K1: counts + per-class per-channel sums, contiguous reads ----------------
// grid (64 chunks, 16 cgroups), block 256 (4 waves).
// Per channel: wave w reads 16 KB sequential (px [w*4096, w*4096+4096)).
// bins[t][21] thread-private -> plain RMW; per-channel tree flush -> global atomic.
__global__ __launch_bounds__(256) void k1_sums(const float* __restrict__ pred,
                                               const unsigned* __restrict__ u8buf,
                                               float* __restrict__ ws) {
    const int t = threadIdx.x;
    const int l = t & 63;
    const int w = t >> 6;
    const int chunk = blockIdx.x;        // 64
    const int cg = blockIdx.y;           // 16
    const int n = chunk >> 4;
    const int choff = (chunk & 15) * CHUNK;

    __shared__ unsigned labw[CHUNK / 4];      // 16 KB packed u8 labels
    __shared__ float bins[256 * 21];          // 21.5 KB thread-private rows
    __shared__ float cnt[16 * 21];            // 1.3 KB replica count hist
    __shared__ float red[4 * 21];             // flush partials

    float* br = &bins[t * 21];
    #pragma unroll
    for (int k = 0; k < KCLS; ++k) br[k] = 0.0f;
    for (int i = t; i < 16 * 21; i += 256) cnt[i] = 0.0f;
    __syncthreads();

    // stage labels: 4096 words / 256 thr = 16 words = 4 uint4 per thread
    {
        const uint4* g4 = (const uint4*)(u8buf + chunk * (CHUNK / 4));
        #pragma unroll
        for (int q = 0; q < 4; ++q) {
            uint4 v = g4[t + q * 256];
            ((uint4*)labw)[t + q * 256] = v;
        }
        // counts: this block counts its 1/16 slice (words [cg*256 + t])
        unsigned cw = ((const unsigned*)(u8buf + chunk * (CHUNK / 4)))[cg * 256 + t];
        float* cr = &cnt[(t & 15) * 21];
        ldsAdd(&cr[cw & 31], 1.0f);
        ldsAdd(&cr[(cw >> 8) & 31], 1.0f);
        ldsAdd(&cr[(cw >> 16) & 31], 1.0f);
        ldsAdd(&cr[(cw >> 24) & 31], 1.0f);
    }
    __syncthreads();

    for (int c4 = 0; c4 < CPG; ++c4) {
        const int c = cg * CPG + c4;
        const float4* src = (const float4*)(pred + (size_t)(n * CCH + c) * HW + choff + w * 4096);
        const unsigned* lwp = &labw[w * 1024];

        // 16 iters in 4 batches of 4, register prefetch
        float4 v0 = src[0], v1 = src[64], v2 = src[128], v3 = src[192];
        unsigned lw0 = lwp[l], lw1 = lwp[64 + l], lw2 = lwp[128 + l], lw3 = lwp[192 + l];
        // note: iter i -> element src[i*64 + l]; batch b covers i = b*4..b*4+3
        // reorganize: do linear iters with 4-deep pipeline
        #pragma unroll 1
        for (int b = 0; b < 4; ++b) {
            // current batch: iters b*4 .. b*4+3 -> elements (b*4+j)*64 + l
            float4 cv[4]; unsigned cl[4];
            #pragma unroll
            for (int j = 0; j < 4; ++j) {
                cv[j] = src[(b * 4 + j) * 64 + l];
                cl[j] = lwp[(b * 4 + j) * 64 + l];
            }
            #pragma unroll
            for (int j = 0; j < 4; ++j) {
                const unsigned lw = cl[j];
                const float4 v = cv[j];
                br[lw & 31] += v.x;
                br[(lw >> 8) & 31] += v.y;
                br[(lw >> 16) & 31] += v.z;
                br[(lw >> 24) & 31] += v.w;
            }
        }
        (void)v0; (void)v1; (void)v2; (void)v3;
        (void)lw0; (void)lw1; (void)lw2; (void)lw3;

        // flush channel c
        __syncthreads();
        if (l < KCLS) {
            float s = 0.0f;
            const int rbase = w * 64;
            #pragma unroll 8
            for (int r = 0; r < 64; ++r) s += bins[(rbase + r) * 21 + l];
            red[w * 21 + l] = s;
        }
        __syncthreads();
        if (t < KCLS) {
            float s = red[t] + red[21 + t] + red[42 + t] + red[63 + t];
            unsafeAtomicAdd(&ws[WS_SUMS + t * CCH + c], s);
        }
        #pragma unroll
        for (int k = 0; k < KCLS; ++k) br[k] = 0.0f;
        __syncthreads();
    }

    if (t < KCLS) {
        float s = 0.0f;
        #pragma unroll
        for (int r = 0; r < 16; ++r) s += cnt[r * 21 + t];
        unsafeAtomicAdd(&ws[WS_COUNTS + t], s);
    }
}

// ---------------- K3: per-pixel pull term (fp32, R7-proven) + center prologue ----------------
// grid: 1024 chunks of 1024 pixels, block 256 (4 px/thread), reversed order.
__global__ __launch_bounds__(256) void k3_var(const float* __restrict__ pred,
                                              const int* __restrict__ tgt,
                                              float* __restrict__ ws) {
    const int t = threadIdx.x;
    const int cid = 1023 - blockIdx.x;
    const int n = cid >> 8;
    const int hwb = (cid & 255) * 1024;

    __shared__ float ct[CCH * 20];       // ct[c*20 + k]
    __shared__ float cntS[KCLS];
    __shared__ float varh[80];

    if (t < KCLS) cntS[t] = ws[WS_COUNTS + t];
    if (t < 80) varh[t] = 0.0f;
    __syncthreads();
    for (int i = t; i < CCH * 20; i += 256) {
        int c = i / 20, k = i % 20;
        ct[i] = (k < KCLS) ? ws[WS_SUMS + k * CCH + c] / fmaxf(cntS[k], 1.0f) : 0.0f;
    }

    const int4 l0 = ((const int4*)(tgt + n * HW + hwb))[t];
    const int lab0 = l0.x, lab1 = l0.y, lab2 = l0.z, lab3 = l0.w;
    float a0 = 0.0f, a1 = 0.0f, a2 = 0.0f, a3 = 0.0f;
    __syncthreads();

    const float* base = pred + (size_t)n * CCH * HW + hwb;
    #pragma unroll 4
    for (int c = 0; c < CCH; ++c) {
        float4 v = ((const float4*)(base + (size_t)c * HW))[t];
        const float* row = &ct[c * 20];
        float m0 = row[lab0], m1 = row[lab1], m2 = row[lab2], m3 = row[lab3];
        float d0 = v.x - m0, d1 = v.y - m1, d2 = v.z - m2, d3 = v.w - m3;
        a0 = fmaf(d0, d0, a0);
        a1 = fmaf(d1, d1, a1);
        a2 = fmaf(d2, d2, a2);
        a3 = fmaf(d3, d3, a3);
    }

    const int rep = (t & 3) * KCLS;
    {
        float d, r;
        d = sqrtf(fmaxf(a0, 1e-12f)); r = d - 0.5f; if (r > 0.0f) ldsAdd(&varh[rep + lab0], r * r);
        d = sqrtf(fmaxf(a1, 1e-12f)); r = d - 0.5f; if (r > 0.0f) ldsAdd(&varh[rep + lab1], r * r);
        d = sqrtf(fmaxf(a2, 1e-12f)); r = d - 0.5f; if (r > 0.0f) ldsAdd(&varh[rep + lab2], r * r);
        d = sqrtf(fmaxf(a3, 1e-12f)); r = d - 0.5f; if (r > 0.0f) ldsAdd(&varh[rep + lab3], r * r);
    }
    __syncthreads();
    if (t < KCLS) {
        float s = varh[t] + varh[19 + t] + varh[38 + t] + varh[57 + t];
        unsafeAtomicAdd(&ws[WS_VARSUM + t], s);
    }
}

// ---------------- K4: centers + push + reg + final combine (1 block) ----------------
__global__ __launch_bounds__(256) void k4_final(const float* __restrict__ ws,
                                                float* __restrict__ out) {
    __shared__ float ct[CCH * 20];
    __shared__ float cntS[KCLS];
    __shared__ float acc[2];
    const int t = threadIdx.x;
    if (t < KCLS) cntS[t] = ws[WS_COUNTS + t];
    if (t < 2) acc[t] = 0.0f;
    __syncthreads();
    for (int i = t; i < CCH * 20; i += 256) {
        int c = i / 20, k = i % 20;
        ct[i] = (k < KCLS) ? ws[WS_SUMS + k * CCH + c] / fmaxf(cntS[k], 1.0f) : 0.0f;
    }
    __syncthreads();

    for (int p = t; p < KCLS * KCLS; p += 256) {
        int i = p / KCLS, j = p % KCLS;
        if (i != j && cntS[i] > 20.0f && cntS[j] > 20.0f) {
            float sq = 0.0f;
            #pragma unroll 8
            for (int c = 0; c < CCH; ++c) {
                float d = ct[c * 20 + i] - ct[c * 20 + j];
                sq = fmaf(d, d, sq);
            }
            float pd = sqrtf(sq);
            float r = 3.0f - pd;        // 2*DELTA - pd
            if (r > 0.0f) atomicAdd(&acc[0], r * r);
        }
    }
    if (t < KCLS && cntS[t] > 20.0f) {
        float sq = 0.0f;
        #pragma unroll 8
        for (int c = 0; c < CCH; ++c) { float v = ct[c * 20 + t]; sq = fmaf(v, v, sq); }
        atomicAdd(&acc[1], sqrtf(sq));
    }
    __syncthreads();

    if (t < 64) {
        float v = 0.0f;
        if (t < KCLS) {
            float c = cntS[t];
            if (c > 20.0f) v = ws[WS_VARSUM + t] / fmaxf(c, 1.0f);
        }
        #pragma unroll
        for (int s = 32; s > 0; s >>= 1) v += __shfl_down(v, s);
        if (t == 0) {
            float nv = 0.0f;
            for (int k = 0; k < KCLS; ++k) nv += (cntS[k] > 20.0f) ? 1.0f : 0.0f;
            float loss_dis = acc[0] / fmaxf(nv * (nv - 1.0f), 1.0f);
            float loss_reg = acc[1] / fmaxf(nv, 1.0f);
            out[0] = v / fmaxf(nv, 1.0f) + loss_dis + 0.001f * loss_reg;
        }
    }
}

extern "C" void kernel_launch(void* const* d_in, const int* in_sizes, int n_in,
                              void* d_out, int out_size, void* d_ws, size_t ws_size,
                              hipStream_t stream) {
    const float* pred = (const float*)d_in[0];
    const int* tgt = (const int*)d_in[1];
    float* ws = (float*)d_ws;
    unsigned* u8buf = (unsigned*)((char*)d_ws + WS_U8_BYTE_OFF);
    float* out = (float*)d_out;

    hipLaunchKernelGGL(k0_prep, dim3(256), dim3(256), 0, stream, tgt, ws, u8buf);
    hipLaunchKernelGGL(k1_sums, dim3(NCHUNK, NCGRP), dim3(256), 0, stream, pred, u8buf, ws);
    hipLaunchKernelGGL(k3_var, dim3(1024), dim3(256), 0, stream, pred, tgt, ws);
    hipLaunchKernelGGL(k4_final, dim3(1), dim3(256), 0, stream, ws, out);
}

// Round 15
// 125.997 us; speedup vs baseline: 2.3503x; 1.0349x over previous
//
#include <hip/hip_runtime.h>

#define KCLS 19
#define CCH 64
#define HW (512*512)
#define NPIX (4*HW)          // 1,048,576 pixels

// K1 geometry: channel-major contiguous
#define CHUNK 16384          // pixels per chunk (16 chunks per image)
#define NCHUNK (NPIX/CHUNK)  // 64
#define NCGRP 16             // channel groups of 4
#define CPG 4

// ws float offsets (stats area)
#define WS_COUNTS  0      // 19
#define WS_SUMS    32     // [k*64+c], 1216
#define WS_VARSUM  1280   // 19
#define WS_NFLOATS 2576
#define WS_U8_BYTE_OFF  16384                      // packed u8 labels, 1 MB
#define WS_FP8_BYTE_OFF (16384 + 1048576)          // fp8 copy of pred (plane layout), 64 MB

typedef float f32x2 __attribute__((ext_vector_type(2)));

__device__ __forceinline__ void ldsAdd(float* p, float v) { unsafeAtomicAdd(p, v); }

// ---------------- K0: zero stats + pack labels to u8 ----------------
__global__ __launch_bounds__(256) void k0_prep(const int* __restrict__ tgt,
                                               float* __restrict__ ws,
                                               unsigned* __restrict__ u8buf) {
    const int j = blockIdx.x * 256 + threadIdx.x;
    if (blockIdx.x == 0) {
        for (int i = threadIdx.x; i < WS_NFLOATS; i += 256) ws[i] = 0.0f;
    }
    const int4* tg4 = (const int4*)tgt;
    unsigned pk[4];
    #pragma unroll
    for (int q = 0; q < 4; ++q) {
        int4 L = tg4[j * 4 + q];
        pk[q] = (unsigned)(L.x & 0xFF) | ((unsigned)(L.y & 0xFF) << 8) |
                ((unsigned)(L.z & 0xFF) << 16) | ((unsigned)(L.w & 0xFF) << 24);
    }
    uint4 o; o.x = pk[0]; o.y = pk[1]; o.z = pk[2]; o.w = pk[3];
    ((uint4*)u8buf)[j] = o;
}

// ---------------- K1: counts + sums (fp32-exact) + fp8 plane copy (NT stores) ----------------
// grid (64 chunks, 16 cgroups), block 256 (4 waves).
// Per channel: wave w reads 16 KB sequential; fp8 word store is lane-consecutive (256 B/instr).
__global__ __launch_bounds__(256) void k1_sums(const float* __restrict__ pred,
                                               const unsigned* __restrict__ u8buf,
                                               float* __restrict__ ws,
                                               unsigned* __restrict__ fp8buf) {
    const int t = threadIdx.x;
    const int l = t & 63;
    const int w = t >> 6;
    const int chunk = blockIdx.x;        // 64
    const int cg = blockIdx.y;           // 16
    const int n = chunk >> 4;
    const int choff = (chunk & 15) * CHUNK;

    __shared__ unsigned labw[CHUNK / 4];      // 16 KB packed u8 labels
    __shared__ float bins[256 * 21];          // 21.5 KB thread-private rows
    __shared__ float cnt[16 * 21];            // 1.3 KB replica count hist
    __shared__ float red[4 * 21];             // flush partials

    float* br = &bins[t * 21];
    #pragma unroll
    for (int k = 0; k < KCLS; ++k) br[k] = 0.0f;
    for (int i = t; i < 16 * 21; i += 256) cnt[i] = 0.0f;
    __syncthreads();

    // stage labels: 4096 words / 256 thr = 4 uint4 per thread; counts on 1/16 slice
    {
        const uint4* g4 = (const uint4*)(u8buf + chunk * (CHUNK / 4));
        #pragma unroll
        for (int q = 0; q < 4; ++q) {
            uint4 v = g4[t + q * 256];
            ((uint4*)labw)[t + q * 256] = v;
        }
        unsigned cw = ((const unsigned*)(u8buf + chunk * (CHUNK / 4)))[cg * 256 + t];
        float* cr = &cnt[(t & 15) * 21];
        ldsAdd(&cr[cw & 31], 1.0f);
        ldsAdd(&cr[(cw >> 8) & 31], 1.0f);
        ldsAdd(&cr[(cw >> 16) & 31], 1.0f);
        ldsAdd(&cr[(cw >> 24) & 31], 1.0f);
    }
    __syncthreads();

    for (int c4 = 0; c4 < CPG; ++c4) {
        const int c = cg * CPG + c4;
        const size_t plane = (size_t)(n * CCH + c) * HW + choff;
        const float4* src = (const float4*)(pred + plane) + w * 1024;
        unsigned* dst8 = fp8buf + (plane >> 2) + w * 1024;
        const unsigned* lwp = &labw[w * 1024];

        #pragma unroll 1
        for (int b = 0; b < 4; ++b) {
            float4 cv[4]; unsigned cl[4];
            #pragma unroll
            for (int j = 0; j < 4; ++j) {
                cv[j] = src[(b * 4 + j) * 64 + l];
                cl[j] = lwp[(b * 4 + j) * 64 + l];
            }
            #pragma unroll
            for (int j = 0; j < 4; ++j) {
                const unsigned lw = cl[j];
                const float4 v = cv[j];
                br[lw & 31] += v.x;
                br[(lw >> 8) & 31] += v.y;
                br[(lw >> 16) & 31] += v.z;
                br[(lw >> 24) & 31] += v.w;
                int pk = 0;
                pk = __builtin_amdgcn_cvt_pk_fp8_f32(v.x, v.y, pk, false);
                pk = __builtin_amdgcn_cvt_pk_fp8_f32(v.z, v.w, pk, true);
                __builtin_nontemporal_store((unsigned)pk, &dst8[(b * 4 + j) * 64 + l]);
            }
        }

        // flush channel c
        __syncthreads();
        if (l < KCLS) {
            float s = 0.0f;
            const int rbase = w * 64;
            #pragma unroll 8
            for (int r = 0; r < 64; ++r) s += bins[(rbase + r) * 21 + l];
            red[w * 21 + l] = s;
        }
        __syncthreads();
        if (t < KCLS) {
            float s = red[t] + red[21 + t] + red[42 + t] + red[63 + t];
            unsafeAtomicAdd(&ws[WS_SUMS + t * CCH + c], s);
        }
        #pragma unroll
        for (int k = 0; k < KCLS; ++k) br[k] = 0.0f;
        __syncthreads();
    }

    if (t < KCLS) {
        float s = 0.0f;
        #pragma unroll
        for (int r = 0; r < 16; ++r) s += cnt[r * 21 + t];
        unsafeAtomicAdd(&ws[WS_COUNTS + t], s);
    }
}

// ---------------- K3: per-pixel pull term from fp8 plane copy ----------------
// grid: 1024 chunks of 1024 pixels, block 256 (4 px/thread), reversed order.
__global__ __launch_bounds__(256) void k3_var(const unsigned* __restrict__ fp8buf,
                                              const int* __restrict__ tgt,
                                              float* __restrict__ ws) {
    const int t = threadIdx.x;
    const int cid = 1023 - blockIdx.x;
    const int n = cid >> 8;
    const int hwb = (cid & 255) * 1024;

    __shared__ float ct[CCH * 20];       // ct[c*20 + k]
    __shared__ float cntS[KCLS];
    __shared__ float varh[80];

    if (t < KCLS) cntS[t] = ws[WS_COUNTS + t];
    if (t < 80) varh[t] = 0.0f;
    __syncthreads();
    for (int i = t; i < CCH * 20; i += 256) {
        int c = i / 20, k = i % 20;
        ct[i] = (k < KCLS) ? ws[WS_SUMS + k * CCH + c] / fmaxf(cntS[k], 1.0f) : 0.0f;
    }

    const int4 l0 = ((const int4*)(tgt + n * HW + hwb))[t];
    const int lab0 = l0.x, lab1 = l0.y, lab2 = l0.z, lab3 = l0.w;
    float a0 = 0.0f, a1 = 0.0f, a2 = 0.0f, a3 = 0.0f;
    __syncthreads();

    const unsigned* base8 = fp8buf + (((size_t)n * CCH * HW + hwb) >> 2);
    #pragma unroll 4
    for (int c = 0; c < CCH; ++c) {
        const unsigned w8 = base8[c * (HW / 4) + t];
        f32x2 lo = __builtin_amdgcn_cvt_pk_f32_fp8(w8, false);
        f32x2 hi = __builtin_amdgcn_cvt_pk_f32_fp8(w8, true);
        const float* row = &ct[c * 20];
        float m0 = row[lab0], m1 = row[lab1], m2 = row[lab2], m3 = row[lab3];
        float d0 = lo.x - m0, d1 = lo.y - m1, d2 = hi.x - m2, d3 = hi.y - m3;
        a0 = fmaf(d0, d0, a0);
        a1 = fmaf(d1, d1, a1);
        a2 = fmaf(d2, d2, a2);
        a3 = fmaf(d3, d3, a3);
    }

    const int rep = (t & 3) * KCLS;
    {
        float d, r;
        d = sqrtf(fmaxf(a0, 1e-12f)); r = d - 0.5f; if (r > 0.0f) ldsAdd(&varh[rep + lab0], r * r);
        d = sqrtf(fmaxf(a1, 1e-12f)); r = d - 0.5f; if (r > 0.0f) ldsAdd(&varh[rep + lab1], r * r);
        d = sqrtf(fmaxf(a2, 1e-12f)); r = d - 0.5f; if (r > 0.0f) ldsAdd(&varh[rep + lab2], r * r);
        d = sqrtf(fmaxf(a3, 1e-12f)); r = d - 0.5f; if (r > 0.0f) ldsAdd(&varh[rep + lab3], r * r);
    }
    __syncthreads();
    if (t < KCLS) {
        float s = varh[t] + varh[19 + t] + varh[38 + t] + varh[57 + t];
        unsafeAtomicAdd(&ws[WS_VARSUM + t], s);
    }
}

// ---------------- K4: centers + push + reg + final combine (1 block) ----------------
__global__ __launch_bounds__(256) void k4_final(const float* __restrict__ ws,
                                                float* __restrict__ out) {
    __shared__ float ct[CCH * 20];
    __shared__ float cntS[KCLS];
    __shared__ float acc[2];
    const int t = threadIdx.x;
    if (t < KCLS) cntS[t] = ws[WS_COUNTS + t];
    if (t < 2) acc[t] = 0.0f;
    __syncthreads();
    for (int i = t; i < CCH * 20; i += 256) {
        int c = i / 20, k = i % 20;
        ct[i] = (k < KCLS) ? ws[WS_SUMS + k * CCH + c] / fmaxf(cntS[k], 1.0f) : 0.0f;
    }
    __syncthreads();

    for (int p = t; p < KCLS * KCLS; p += 256) {
        int i = p / KCLS, j = p % KCLS;
        if (i != j && cntS[i] > 20.0f && cntS[j] > 20.0f) {
            float sq = 0.0f;
            #pragma unroll 8
            for (int c = 0; c < CCH; ++c) {
                float d = ct[c * 20 + i] - ct[c * 20 + j];
                sq = fmaf(d, d, sq);
            }
            float pd = sqrtf(sq);
            float r = 3.0f - pd;        // 2*DELTA - pd
            if (r > 0.0f) atomicAdd(&acc[0], r * r);
        }
    }
    if (t < KCLS && cntS[t] > 20.0f) {
        float sq = 0.0f;
        #pragma unroll 8
        for (int c = 0; c < CCH; ++c) { float v = ct[c * 20 + t]; sq = fmaf(v, v, sq); }
        atomicAdd(&acc[1], sqrtf(sq));
    }
    __syncthreads();

    if (t < 64) {
        float v = 0.0f;
        if (t < KCLS) {
            float c = cntS[t];
            if (c > 20.0f) v = ws[WS_VARSUM + t] / fmaxf(c, 1.0f);
        }
        #pragma unroll
        for (int s = 32; s > 0; s >>= 1) v += __shfl_down(v, s);
        if (t == 0) {
            float nv = 0.0f;
            for (int k = 0; k < KCLS; ++k) nv += (cntS[k] > 20.0f) ? 1.0f : 0.0f;
            float loss_dis = acc[0] / fmaxf(nv * (nv - 1.0f), 1.0f);
            float loss_reg = acc[1] / fmaxf(nv, 1.0f);
            out[0] = v / fmaxf(nv, 1.0f) + loss_dis + 0.001f * loss_reg;
        }
    }
}

extern "C" void kernel_launch(void* const* d_in, const int* in_sizes, int n_in,
                              void* d_out, int out_size, void* d_ws, size_t ws_size,
                              hipStream_t stream) {
    const float* pred = (const float*)d_in[0];
    const int* tgt = (const int*)d_in[1];
    float* ws = (float*)d_ws;
    unsigned* u8buf = (unsigned*)((char*)d_ws + WS_U8_BYTE_OFF);
    unsigned* fp8buf = (unsigned*)((char*)d_ws + WS_FP8_BYTE_OFF);
    float* out = (float*)d_out;

    hipLaunchKernelGGL(k0_prep, dim3(256), dim3(256), 0, stream, tgt, ws, u8buf);
    hipLaunchKernelGGL(k1_sums, dim3(NCHUNK, NCGRP), dim3(256), 0, stream, pred, u8buf, ws, fp8buf);
    hipLaunchKernelGGL(k3_var, dim3(1024), dim3(256), 0, stream, fp8buf, tgt, ws);
    hipLaunchKernelGGL(k4_final, dim3(1), dim3(256), 0, stream, ws, out);
}

// Round 16
// 124.753 us; speedup vs baseline: 2.3737x; 1.0100x over previous
//
#include <hip/hip_runtime.h>

#define KCLS 19
#define CCH 64
#define HW (512*512)
#define NPIX (4*HW)          // 1,048,576 pixels

// K1 geometry: channel-major contiguous
#define CHUNK 16384          // pixels per chunk (16 chunks per image)
#define NCHUNK (NPIX/CHUNK)  // 64
#define NCGRP 16             // channel groups of 4
#define CPG 4

// ws float offsets (stats area)
#define WS_COUNTS  0      // 19
#define WS_SUMS    32     // [k*64+c], 1216
#define WS_VARSUM  1280   // 19
#define WS_NFLOATS 2576
#define WS_U8_BYTE_OFF  16384                      // packed u8 labels, 1 MB
#define WS_FP8_BYTE_OFF (16384 + 1048576)          // fp8 copy of pred (plane layout), 64 MB

typedef float f32x2 __attribute__((ext_vector_type(2)));

__device__ __forceinline__ void ldsAdd(float* p, float v) { unsafeAtomicAdd(p, v); }

// ---------------- K0: zero stats + pack labels to u8 ----------------
__global__ __launch_bounds__(256) void k0_prep(const int* __restrict__ tgt,
                                               float* __restrict__ ws,
                                               unsigned* __restrict__ u8buf) {
    const int j = blockIdx.x * 256 + threadIdx.x;
    if (blockIdx.x == 0) {
        for (int i = threadIdx.x; i < WS_NFLOATS; i += 256) ws[i] = 0.0f;
    }
    const int4* tg4 = (const int4*)tgt;
    unsigned pk[4];
    #pragma unroll
    for (int q = 0; q < 4; ++q) {
        int4 L = tg4[j * 4 + q];
        pk[q] = (unsigned)(L.x & 0xFF) | ((unsigned)(L.y & 0xFF) << 8) |
                ((unsigned)(L.z & 0xFF) << 16) | ((unsigned)(L.w & 0xFF) << 24);
    }
    uint4 o; o.x = pk[0]; o.y = pk[1]; o.z = pk[2]; o.w = pk[3];
    ((uint4*)u8buf)[j] = o;
}

// ---------------- K1: counts + sums (fp32-exact) + fp8 plane copy (NT stores) ----------------
// grid (64 chunks, 16 cgroups), block 256 (4 waves).
__global__ __launch_bounds__(256) void k1_sums(const float* __restrict__ pred,
                                               const unsigned* __restrict__ u8buf,
                                               float* __restrict__ ws,
                                               unsigned* __restrict__ fp8buf) {
    const int t = threadIdx.x;
    const int l = t & 63;
    const int w = t >> 6;
    const int chunk = blockIdx.x;        // 64
    const int cg = blockIdx.y;           // 16
    const int n = chunk >> 4;
    const int choff = (chunk & 15) * CHUNK;

    __shared__ unsigned labw[CHUNK / 4];      // 16 KB packed u8 labels
    __shared__ float bins[256 * 21];          // 21.5 KB thread-private rows
    __shared__ float cnt[16 * 21];            // 1.3 KB replica count hist
    __shared__ float red[4 * 21];             // flush partials

    float* br = &bins[t * 21];
    #pragma unroll
    for (int k = 0; k < KCLS; ++k) br[k] = 0.0f;
    for (int i = t; i < 16 * 21; i += 256) cnt[i] = 0.0f;
    __syncthreads();

    {
        const uint4* g4 = (const uint4*)(u8buf + chunk * (CHUNK / 4));
        #pragma unroll
        for (int q = 0; q < 4; ++q) {
            uint4 v = g4[t + q * 256];
            ((uint4*)labw)[t + q * 256] = v;
        }
        unsigned cw = ((const unsigned*)(u8buf + chunk * (CHUNK / 4)))[cg * 256 + t];
        float* cr = &cnt[(t & 15) * 21];
        ldsAdd(&cr[cw & 31], 1.0f);
        ldsAdd(&cr[(cw >> 8) & 31], 1.0f);
        ldsAdd(&cr[(cw >> 16) & 31], 1.0f);
        ldsAdd(&cr[(cw >> 24) & 31], 1.0f);
    }
    __syncthreads();

    for (int c4 = 0; c4 < CPG; ++c4) {
        const int c = cg * CPG + c4;
        const size_t plane = (size_t)(n * CCH + c) * HW + choff;
        const float4* src = (const float4*)(pred + plane) + w * 1024;
        unsigned* dst8 = fp8buf + (plane >> 2) + w * 1024;
        const unsigned* lwp = &labw[w * 1024];

        #pragma unroll 1
        for (int b = 0; b < 4; ++b) {
            float4 cv[4]; unsigned cl[4];
            #pragma unroll
            for (int j = 0; j < 4; ++j) {
                cv[j] = src[(b * 4 + j) * 64 + l];
                cl[j] = lwp[(b * 4 + j) * 64 + l];
            }
            #pragma unroll
            for (int j = 0; j < 4; ++j) {
                const unsigned lw = cl[j];
                const float4 v = cv[j];
                br[lw & 31] += v.x;
                br[(lw >> 8) & 31] += v.y;
                br[(lw >> 16) & 31] += v.z;
                br[(lw >> 24) & 31] += v.w;
                int pk = 0;
                pk = __builtin_amdgcn_cvt_pk_fp8_f32(v.x, v.y, pk, false);
                pk = __builtin_amdgcn_cvt_pk_fp8_f32(v.z, v.w, pk, true);
                __builtin_nontemporal_store((unsigned)pk, &dst8[(b * 4 + j) * 64 + l]);
            }
        }

        // flush channel c
        __syncthreads();
        if (l < KCLS) {
            float s = 0.0f;
            const int rbase = w * 64;
            #pragma unroll 8
            for (int r = 0; r < 64; ++r) s += bins[(rbase + r) * 21 + l];
            red[w * 21 + l] = s;
        }
        __syncthreads();
        if (t < KCLS) {
            float s = red[t] + red[21 + t] + red[42 + t] + red[63 + t];
            unsafeAtomicAdd(&ws[WS_SUMS + t * CCH + c], s);
        }
        #pragma unroll
        for (int k = 0; k < KCLS; ++k) br[k] = 0.0f;
        __syncthreads();
    }

    if (t < KCLS) {
        float s = 0.0f;
        #pragma unroll
        for (int r = 0; r < 16; ++r) s += cnt[r * 21 + t];
        unsafeAtomicAdd(&ws[WS_COUNTS + t], s);
    }
}

// ---------------- K3: pull term from fp8 plane copy; 8-deep channel prefetch ----------------
// grid: 1024 chunks of 1024 pixels, block 256 (4 px/thread), reversed order.
__global__ __launch_bounds__(256) void k3_var(const unsigned* __restrict__ fp8buf,
                                              const int* __restrict__ tgt,
                                              float* __restrict__ ws) {
    const int t = threadIdx.x;
    const int cid = 1023 - blockIdx.x;
    const int n = cid >> 8;
    const int hwb = (cid & 255) * 1024;

    __shared__ float ct[CCH * 20];       // ct[c*20 + k]
    __shared__ float cntS[KCLS];
    __shared__ float varh[80];

    if (t < KCLS) cntS[t] = ws[WS_COUNTS + t];
    if (t < 80) varh[t] = 0.0f;
    __syncthreads();
    for (int i = t; i < CCH * 20; i += 256) {
        int c = i / 20, k = i % 20;
        ct[i] = (k < KCLS) ? ws[WS_SUMS + k * CCH + c] / fmaxf(cntS[k], 1.0f) : 0.0f;
    }

    const int4 l0 = ((const int4*)(tgt + n * HW + hwb))[t];
    const int lab0 = l0.x, lab1 = l0.y, lab2 = l0.z, lab3 = l0.w;
    float a0 = 0.0f, a1 = 0.0f, a2 = 0.0f, a3 = 0.0f;
    __syncthreads();

    const unsigned* base8 = fp8buf + (((size_t)n * CCH * HW + hwb) >> 2);

    // 8 batches of 8 channels, next-batch register prefetch (8 loads in flight)
    unsigned wb[8], nb[8];
    #pragma unroll
    for (int j = 0; j < 8; ++j) wb[j] = base8[j * (HW / 4) + t];

    #pragma unroll 1
    for (int cb = 0; cb < 8; ++cb) {
        if (cb < 7) {
            #pragma unroll
            for (int j = 0; j < 8; ++j) nb[j] = base8[((cb + 1) * 8 + j) * (HW / 4) + t];
        }
        const int cbase = cb * 8;
        #pragma unroll
        for (int j = 0; j < 8; ++j) {
            const unsigned w8 = wb[j];
            f32x2 lo = __builtin_amdgcn_cvt_pk_f32_fp8(w8, false);
            f32x2 hi = __builtin_amdgcn_cvt_pk_f32_fp8(w8, true);
            const float* row = &ct[(cbase + j) * 20];
            float m0 = row[lab0], m1 = row[lab1], m2 = row[lab2], m3 = row[lab3];
            float d0 = lo.x - m0, d1 = lo.y - m1, d2 = hi.x - m2, d3 = hi.y - m3;
            a0 = fmaf(d0, d0, a0);
            a1 = fmaf(d1, d1, a1);
            a2 = fmaf(d2, d2, a2);
            a3 = fmaf(d3, d3, a3);
        }
        #pragma unroll
        for (int j = 0; j < 8; ++j) wb[j] = nb[j];
    }

    const int rep = (t & 3) * KCLS;
    {
        float d, r;
        d = sqrtf(fmaxf(a0, 1e-12f)); r = d - 0.5f; if (r > 0.0f) ldsAdd(&varh[rep + lab0], r * r);
        d = sqrtf(fmaxf(a1, 1e-12f)); r = d - 0.5f; if (r > 0.0f) ldsAdd(&varh[rep + lab1], r * r);
        d = sqrtf(fmaxf(a2, 1e-12f)); r = d - 0.5f; if (r > 0.0f) ldsAdd(&varh[rep + lab2], r * r);
        d = sqrtf(fmaxf(a3, 1e-12f)); r = d - 0.5f; if (r > 0.0f) ldsAdd(&varh[rep + lab3], r * r);
    }
    __syncthreads();
    if (t < KCLS) {
        float s = varh[t] + varh[19 + t] + varh[38 + t] + varh[57 + t];
        unsafeAtomicAdd(&ws[WS_VARSUM + t], s);
    }
}

// ---------------- K4: centers + push + reg + final combine (1 block) ----------------
__global__ __launch_bounds__(256) void k4_final(const float* __restrict__ ws,
                                                float* __restrict__ out) {
    __shared__ float ct[CCH * 20];
    __shared__ float cntS[KCLS];
    __shared__ float acc[2];
    const int t = threadIdx.x;
    if (t < KCLS) cntS[t] = ws[WS_COUNTS + t];
    if (t < 2) acc[t] = 0.0f;
    __syncthreads();
    for (int i = t; i < CCH * 20; i += 256) {
        int c = i / 20, k = i % 20;
        ct[i] = (k < KCLS) ? ws[WS_SUMS + k * CCH + c] / fmaxf(cntS[k], 1.0f) : 0.0f;
    }
    __syncthreads();

    for (int p = t; p < KCLS * KCLS; p += 256) {
        int i = p / KCLS, j = p % KCLS;
        if (i != j && cntS[i] > 20.0f && cntS[j] > 20.0f) {
            float sq = 0.0f;
            #pragma unroll 8
            for (int c = 0; c < CCH; ++c) {
                float d = ct[c * 20 + i] - ct[c * 20 + j];
                sq = fmaf(d, d, sq);
            }
            float pd = sqrtf(sq);
            float r = 3.0f - pd;        // 2*DELTA - pd
            if (r > 0.0f) atomicAdd(&acc[0], r * r);
        }
    }
    if (t < KCLS && cntS[t] > 20.0f) {
        float sq = 0.0f;
        #pragma unroll 8
        for (int c = 0; c < CCH; ++c) { float v = ct[c * 20 + t]; sq = fmaf(v, v, sq); }
        atomicAdd(&acc[1], sqrtf(sq));
    }
    __syncthreads();

    if (t < 64) {
        float v = 0.0f;
        if (t < KCLS) {
            float c = cntS[t];
            if (c > 20.0f) v = ws[WS_VARSUM + t] / fmaxf(c, 1.0f);
        }
        #pragma unroll
        for (int s = 32; s > 0; s >>= 1) v += __shfl_down(v, s);
        if (t == 0) {
            float nv = 0.0f;
            for (int k = 0; k < KCLS; ++k) nv += (cntS[k] > 20.0f) ? 1.0f : 0.0f;
            float loss_dis = acc[0] / fmaxf(nv * (nv - 1.0f), 1.0f);
            float loss_reg = acc[1] / fmaxf(nv, 1.0f);
            out[0] = v / fmaxf(nv, 1.0f) + loss_dis + 0.001f * loss_reg;
        }
    }
}

extern "C" void kernel_launch(void* const* d_in, const int* in_sizes, int n_in,
                              void* d_out, int out_size, void* d_ws, size_t ws_size,
                              hipStream_t stream) {
    const float* pred = (const float*)d_in[0];
    const int* tgt = (const int*)d_in[1];
    float* ws = (float*)d_ws;
    unsigned* u8buf = (unsigned*)((char*)d_ws + WS_U8_BYTE_OFF);
    unsigned* fp8buf = (unsigned*)((char*)d_ws + WS_FP8_BYTE_OFF);
    float* out = (float*)d_out;

    hipLaunchKernelGGL(k0_prep, dim3(256), dim3(256), 0, stream, tgt, ws, u8buf);
    hipLaunchKernelGGL(k1_sums, dim3(NCHUNK, NCGRP), dim3(256), 0, stream, pred, u8buf, ws, fp8buf);
    hipLaunchKernelGGL(k3_var, dim3(1024), dim3(256), 0, stream, fp8buf, tgt, ws);
    hipLaunchKernelGGL(k4_final, dim3(1), dim3(256), 0, stream, ws, out);
}